// Round 1
// baseline (562.705 us; speedup 1.0000x reference)
//
#include <hip/hip_runtime.h>
#include <hip/hip_bf16.h>

#define NF 32      // fields
#define ED 64      // emb dim
#define AD 32      // attention dim
#define FD 50000   // field vocab
#define ROWP 68    // padded LDS emb row stride (floats): bank=(4*row+off)%32 -> <=2-way
#define SCP 36     // padded score row stride

typedef __attribute__((ext_vector_type(8))) short bf16x8;
typedef __attribute__((ext_vector_type(4))) float f32x4;

__device__ __forceinline__ short f2bf(float f) {
    union { float f; unsigned u; } v; v.f = f;
    unsigned r = v.u + 0x7fffu + ((v.u >> 16) & 1u);   // RNE
    return (short)(r >> 16);
}

__global__ __launch_bounds__(256) void afm_kernel(
    const int* __restrict__ x,
    const float* __restrict__ emb_table,
    const float* __restrict__ lin_table,
    const float* __restrict__ lin_bias,
    const float* __restrict__ W1,
    const float* __restrict__ b1,
    const float* __restrict__ w2,
    const float* __restrict__ proj_w,
    float* __restrict__ out)
{
    __shared__ float s_emb[NF * ROWP];   // 8704 B
    __shared__ float s_sc[NF * SCP];     // 4608 B: scores -> exp(scores) (attn, unnormalized)
    __shared__ float s_lin[NF];
    __shared__ float s_red[8];

    const int t    = threadIdx.x;
    const int lane = t & 63;
    const int wave = t >> 6;
    const int l15  = lane & 15;
    const int quad = lane >> 4;
    const int s    = blockIdx.x;

    // ---- stage 1: gather embeddings (coalesced: 8 threads per 256B row), lin term, init scores
    {
        const int row = t >> 3, part = t & 7;
        const int gidx = x[s * NF + row] + row * FD;
        const float* rp = emb_table + (size_t)gidx * ED + part * 8;
        float4 a = *(const float4*)rp;
        float4 b = *(const float4*)(rp + 4);
        *(float4*)(s_emb + row * ROWP + part * 8)     = a;
        *(float4*)(s_emb + row * ROWP + part * 8 + 4) = b;
        if (part == 0) s_lin[row] = lin_table[gidx];
    }
    for (int idx = t; idx < NF * SCP; idx += 256) s_sc[idx] = -1e30f;

    // ---- W1 as bf16 B-fragments (B[k=quad*8+jj][n=l15+16*nt], kk selects k-half); b1/w2 regs
    bf16x8 w1f[2][2];
    #pragma unroll
    for (int kk = 0; kk < 2; ++kk)
        #pragma unroll
        for (int nt = 0; nt < 2; ++nt) {
            bf16x8 f;
            #pragma unroll
            for (int jj = 0; jj < 8; ++jj)
                f[jj] = f2bf(W1[(kk * 32 + quad * 8 + jj) * AD + nt * 16 + l15]);
            w1f[kk][nt] = f;
        }
    const float b1v0 = b1[l15], b1v1 = b1[16 + l15];
    const float w2v0 = w2[l15], w2v1 = w2[16 + l15];

    __syncthreads();

    // ---- E fragments in registers (fp32): lane holds e_{16*jb+l15}[kk*32+quad*8+jj]
    float ef[2][2][8];
    #pragma unroll
    for (int jb = 0; jb < 2; ++jb)
        #pragma unroll
        for (int kk = 0; kk < 2; ++kk) {
            const float* p = s_emb + (16 * jb + l15) * ROWP + kk * 32 + quad * 8;
            float4 a = *(const float4*)p;
            float4 b = *(const float4*)(p + 4);
            ef[jb][kk][0] = a.x; ef[jb][kk][1] = a.y; ef[jb][kk][2] = a.z; ef[jb][kk][3] = a.w;
            ef[jb][kk][4] = b.x; ef[jb][kk][5] = b.y; ef[jb][kk][6] = b.z; ef[jb][kk][7] = b.w;
        }

    // ---- pair-interaction GEMMs: tile (i, jb): rows j = 16*jb + m, A[m][k] = e_i[k]*e_j[k]
    for (int i = wave; i < 32; i += 4) {
        float ei[2][8];
        #pragma unroll
        for (int kk = 0; kk < 2; ++kk) {
            const float* p = s_emb + i * ROWP + kk * 32 + quad * 8;  // broadcast within quad
            float4 a = *(const float4*)p;
            float4 b = *(const float4*)(p + 4);
            ei[kk][0]=a.x; ei[kk][1]=a.y; ei[kk][2]=a.z; ei[kk][3]=a.w;
            ei[kk][4]=b.x; ei[kk][5]=b.y; ei[kk][6]=b.z; ei[kk][7]=b.w;
        }
        #pragma unroll
        for (int jb = 0; jb < 2; ++jb) {
            if (jb * 16 + 15 <= i) continue;    // no j>i rows in this tile
            f32x4 acc0 = {0.f,0.f,0.f,0.f}, acc1 = {0.f,0.f,0.f,0.f};
            #pragma unroll
            for (int kk = 0; kk < 2; ++kk) {
                bf16x8 af;
                #pragma unroll
                for (int jj = 0; jj < 8; ++jj)
                    af[jj] = f2bf(ei[kk][jj] * ef[jb][kk][jj]);
                acc0 = __builtin_amdgcn_mfma_f32_16x16x32_bf16(af, w1f[kk][0], acc0, 0, 0, 0);
                acc1 = __builtin_amdgcn_mfma_f32_16x16x32_bf16(af, w1f[kk][1], acc1, 0, 0, 0);
            }
            // epilogue: h = relu(acc + b1); score = h . w2 ; reduce over 16 cols (lanes l15)
            float4 scv;
            #pragma unroll
            for (int r = 0; r < 4; ++r) {
                float v = fmaxf(acc0[r] + b1v0, 0.f) * w2v0
                        + fmaxf(acc1[r] + b1v1, 0.f) * w2v1;
                v += __shfl_xor(v, 1);
                v += __shfl_xor(v, 2);
                v += __shfl_xor(v, 4);
                v += __shfl_xor(v, 8);
                const int j = jb * 16 + quad * 4 + r;  // C/D: row = quad*4 + reg
                (&scv.x)[r] = (j > i) ? v : -1e30f;
            }
            if (l15 == 0)
                *(float4*)(s_sc + i * SCP + jb * 16 + quad * 4) = scv;
        }
    }
    __syncthreads();

    // ---- softmax over score matrix (invalid slots are -1e30 -> exp = 0)
    float mx = -1e30f;
    for (int idx = t; idx < NF * SCP; idx += 256) mx = fmaxf(mx, s_sc[idx]);
    #pragma unroll
    for (int d = 1; d < 64; d <<= 1) mx = fmaxf(mx, __shfl_xor(mx, d));
    if (lane == 0) s_red[wave] = mx;
    __syncthreads();
    mx = fmaxf(fmaxf(s_red[0], s_red[1]), fmaxf(s_red[2], s_red[3]));
    float lsum = 0.f;
    for (int idx = t; idx < NF * SCP; idx += 256) {
        float e = __expf(s_sc[idx] - mx);
        s_sc[idx] = e;
        lsum += e;
    }
    #pragma unroll
    for (int d = 1; d < 64; d <<= 1) lsum += __shfl_xor(lsum, d);
    if (lane == 0) s_red[4 + wave] = lsum;
    __syncthreads();

    // ---- U = Attn(unnorm) @ E via MFMA; wave w owns d-cols 16w..16w+15
    const int dcol = wave * 16 + l15;
    bf16x8 bE;
    #pragma unroll
    for (int jj = 0; jj < 8; ++jj)
        bE[jj] = f2bf(s_emb[(quad * 8 + jj) * ROWP + dcol]);
    float sec = 0.f;
    #pragma unroll
    for (int mt = 0; mt < 2; ++mt) {
        const float* ap = s_sc + (16 * mt + l15) * SCP + quad * 8;
        float4 a0 = *(const float4*)ap;
        float4 a1 = *(const float4*)(ap + 4);
        bf16x8 aA;
        aA[0]=f2bf(a0.x); aA[1]=f2bf(a0.y); aA[2]=f2bf(a0.z); aA[3]=f2bf(a0.w);
        aA[4]=f2bf(a1.x); aA[5]=f2bf(a1.y); aA[6]=f2bf(a1.z); aA[7]=f2bf(a1.w);
        f32x4 u = {0.f,0.f,0.f,0.f};
        u = __builtin_amdgcn_mfma_f32_16x16x32_bf16(aA, bE, u, 0, 0, 0);
        #pragma unroll
        for (int r = 0; r < 4; ++r)
            sec += u[r] * s_emb[(16 * mt + quad * 4 + r) * ROWP + dcol]; // e_i[d]*u_i[d]
    }
    sec *= proj_w[dcol];
    #pragma unroll
    for (int d = 1; d < 64; d <<= 1) sec += __shfl_xor(sec, d);
    if (lane == 0) s_red[wave] = sec;   // slots 0..3 free: max already consumed
    __syncthreads();

    if (t == 0) {
        float S = s_red[4] + s_red[5] + s_red[6] + s_red[7];
        float second = (s_red[0] + s_red[1] + s_red[2] + s_red[3]) / S;
        float first = lin_bias[0];
        #pragma unroll
        for (int f = 0; f < NF; ++f) first += s_lin[f];
        float y = first + second;
        out[s] = 1.f / (1.f + __expf(-y));
    }
}

extern "C" void kernel_launch(void* const* d_in, const int* in_sizes, int n_in,
                              void* d_out, int out_size, void* d_ws, size_t ws_size,
                              hipStream_t stream) {
    const int*   x         = (const int*)d_in[0];
    const float* emb_table = (const float*)d_in[1];
    const float* lin_table = (const float*)d_in[2];
    const float* lin_bias  = (const float*)d_in[3];
    const float* W1        = (const float*)d_in[4];
    const float* b1        = (const float*)d_in[5];
    const float* w2        = (const float*)d_in[6];
    const float* proj_w    = (const float*)d_in[7];
    float* out = (float*)d_out;

    afm_kernel<<<out_size, 256, 0, stream>>>(x, emb_table, lin_table, lin_bias,
                                             W1, b1, w2, proj_w, out);
}

// Round 2
// 557.645 us; speedup vs baseline: 1.0091x; 1.0091x over previous
//
#include <hip/hip_runtime.h>
#include <hip/hip_bf16.h>

#define NF 32      // fields
#define ED 64      // emb dim
#define AD 32      // attention dim
#define FD 50000   // field vocab
#define ROWP 68    // padded LDS emb row stride (floats): bank=(4*row+off)%32 -> <=2-way
#define SCP 36     // padded score row stride

typedef __attribute__((ext_vector_type(8))) short bf16x8;
typedef __attribute__((ext_vector_type(4))) float f32x4;

__device__ __forceinline__ short f2bf(float f) {
    union { float f; unsigned u; } v; v.f = f;
    unsigned r = v.u + 0x7fffu + ((v.u >> 16) & 1u);   // RNE
    return (short)(r >> 16);
}

// 8 floats -> 8 bf16 via packed HW converts (v_cvt_pk_bf16_f32)
__device__ __forceinline__ bf16x8 pack8(const float* p) {
    bf16x8 r;
#pragma unroll
    for (int i = 0; i < 4; ++i) {
        __hip_bfloat162 h = __float22bfloat162_rn(make_float2(p[2*i], p[2*i+1]));
        short2 s2 = *reinterpret_cast<short2*>(&h);
        r[2*i] = s2.x; r[2*i+1] = s2.y;
    }
    return r;
}

// One-wave setup: pre-pack W1 (64x32 fp32) into bf16 MFMA B-fragment layout.
// ws layout: [(kk*2+nt)*64 + lane] * 8 shorts (16B per lane-fragment).
__global__ __launch_bounds__(64) void prep_w1(const float* __restrict__ W1,
                                              short* __restrict__ w1ws) {
    const int lane = threadIdx.x;
    const int l15 = lane & 15, quad = lane >> 4;
#pragma unroll
    for (int kk = 0; kk < 2; ++kk)
#pragma unroll
        for (int nt = 0; nt < 2; ++nt) {
            bf16x8 f;
#pragma unroll
            for (int jj = 0; jj < 8; ++jj)
                f[jj] = f2bf(W1[(kk * 32 + quad * 8 + jj) * AD + nt * 16 + l15]);
            *(bf16x8*)(w1ws + ((kk * 2 + nt) * 64 + lane) * 8) = f;
        }
}

__global__ __launch_bounds__(256) void afm_kernel(
    const int* __restrict__ x,
    const float* __restrict__ emb_table,
    const float* __restrict__ lin_table,
    const float* __restrict__ lin_bias,
    const short* __restrict__ w1ws,
    const float* __restrict__ b1,
    const float* __restrict__ w2,
    const float* __restrict__ proj_w,
    float* __restrict__ out)
{
    __shared__ float s_emb[NF * ROWP];   // 8704 B
    __shared__ float s_sc[NF * SCP];     // unnormalized attn: exp(score), 0 where j<=i
    __shared__ float s_lin[NF];
    __shared__ float s_red[8];

    const int t    = threadIdx.x;
    const int lane = t & 63;
    const int wave = t >> 6;
    const int l15  = lane & 15;
    const int quad = lane >> 4;
    const int s    = blockIdx.x;

    // W1 fragments: 4 coalesced 16B loads from ws (L2-hit, prepacked)
    const bf16x8* wp = (const bf16x8*)w1ws;
    bf16x8 w1f[2][2];
    w1f[0][0] = wp[0 * 64 + lane];
    w1f[0][1] = wp[1 * 64 + lane];
    w1f[1][0] = wp[2 * 64 + lane];
    w1f[1][1] = wp[3 * 64 + lane];
    const float b1v0 = b1[l15], b1v1 = b1[16 + l15];
    const float w2v0 = w2[l15], w2v1 = w2[16 + l15];

    // ---- stage 1: gather embeddings (coalesced: 8 threads per 256B row), lin, zero scores
    {
        const int row = t >> 3, part = t & 7;
        const int gidx = x[s * NF + row] + row * FD;
        const float* rp = emb_table + (size_t)gidx * ED + part * 8;
        float4 a = *(const float4*)rp;
        float4 b = *(const float4*)(rp + 4);
        *(float4*)(s_emb + row * ROWP + part * 8)     = a;
        *(float4*)(s_emb + row * ROWP + part * 8 + 4) = b;
        if (part == 0) s_lin[row] = lin_table[gidx];
    }
    for (int idx = t; idx < NF * SCP; idx += 256) s_sc[idx] = 0.f;
    __syncthreads();

    // ---- E fragments (fp32): lane holds e_{16*jb+l15}[kk*32+quad*8+jj]
    float ef[2][2][8];
#pragma unroll
    for (int jb = 0; jb < 2; ++jb)
#pragma unroll
        for (int kk = 0; kk < 2; ++kk) {
            const float* p = s_emb + (16 * jb + l15) * ROWP + kk * 32 + quad * 8;
            *(float4*)&ef[jb][kk][0] = *(const float4*)p;
            *(float4*)&ef[jb][kk][4] = *(const float4*)(p + 4);
        }

    // ---- pair-interaction GEMMs with fused exp epilogue
    float lsum = 0.f;   // 16x-duplicated partial softmax denominator
    for (int i = wave; i < NF; i += 4) {
        float ei[2][8];
#pragma unroll
        for (int kk = 0; kk < 2; ++kk) {
            const float* p = s_emb + i * ROWP + kk * 32 + quad * 8;  // quad-broadcast
            *(float4*)&ei[kk][0] = *(const float4*)p;
            *(float4*)&ei[kk][4] = *(const float4*)(p + 4);
        }
#pragma unroll
        for (int jb = 0; jb < 2; ++jb) {
            if (jb * 16 + 15 <= i) continue;    // tile has no j>i rows
            f32x4 acc0 = {0.f,0.f,0.f,0.f}, acc1 = {0.f,0.f,0.f,0.f};
#pragma unroll
            for (int kk = 0; kk < 2; ++kk) {
                float pr[8];
#pragma unroll
                for (int z = 0; z < 8; ++z) pr[z] = ei[kk][z] * ef[jb][kk][z];
                bf16x8 af = pack8(pr);
                acc0 = __builtin_amdgcn_mfma_f32_16x16x32_bf16(af, w1f[kk][0], acc0, 0, 0, 0);
                acc1 = __builtin_amdgcn_mfma_f32_16x16x32_bf16(af, w1f[kk][1], acc1, 0, 0, 0);
            }
            // h = relu(acc + b1); score = h.w2; 16-lane reduce; exp inline
            float scv[4];
#pragma unroll
            for (int r = 0; r < 4; ++r) {
                float v = fmaxf(acc0[r] + b1v0, 0.f) * w2v0
                        + fmaxf(acc1[r] + b1v1, 0.f) * w2v1;
                v += __shfl_xor(v, 1);
                v += __shfl_xor(v, 2);
                v += __shfl_xor(v, 4);
                v += __shfl_xor(v, 8);
                const int j = jb * 16 + quad * 4 + r;  // C/D: row = quad*4 + reg
                float e = (j > i) ? __expf(v) : 0.f;   // scores ~1e-4: no max needed
                lsum += e;
                scv[r] = e;
            }
            if (l15 == 0)
                *(float4*)(s_sc + i * SCP + jb * 16 + quad * 4) = *(float4*)scv;
        }
    }
#pragma unroll
    for (int d = 1; d < 64; d <<= 1) lsum += __shfl_xor(lsum, d);
    if (lane == 0) s_red[4 + wave] = lsum;   // = 16 * true partial sum
    __syncthreads();

    // ---- U = Attn(unnorm) @ E via MFMA; wave w owns d-cols 16w..16w+15
    const int dcol = wave * 16 + l15;
    float bEv[8];
#pragma unroll
    for (int jj = 0; jj < 8; ++jj)
        bEv[jj] = s_emb[(quad * 8 + jj) * ROWP + dcol];
    bf16x8 bE = pack8(bEv);
    float sec = 0.f;
#pragma unroll
    for (int mt = 0; mt < 2; ++mt) {
        const float* ap = s_sc + (16 * mt + l15) * SCP + quad * 8;
        float av[8];
        *(float4*)&av[0] = *(const float4*)ap;
        *(float4*)&av[4] = *(const float4*)(ap + 4);
        bf16x8 aA = pack8(av);
        f32x4 u = {0.f,0.f,0.f,0.f};
        u = __builtin_amdgcn_mfma_f32_16x16x32_bf16(aA, bE, u, 0, 0, 0);
#pragma unroll
        for (int r = 0; r < 4; ++r)
            sec += u[r] * s_emb[(16 * mt + quad * 4 + r) * ROWP + dcol]; // e_i[d]*u_i[d]
    }
    sec *= proj_w[dcol];
#pragma unroll
    for (int d = 1; d < 64; d <<= 1) sec += __shfl_xor(sec, d);
    if (lane == 0) s_red[wave] = sec;
    __syncthreads();

    if (t == 0) {
        float S = (s_red[4] + s_red[5] + s_red[6] + s_red[7]) * (1.f / 16.f);
        float second = (s_red[0] + s_red[1] + s_red[2] + s_red[3]) / S;
        float first = lin_bias[0];
#pragma unroll
        for (int f = 0; f < NF; ++f) first += s_lin[f];
        float y = first + second;
        out[s] = 1.f / (1.f + __expf(-y));
    }
}

extern "C" void kernel_launch(void* const* d_in, const int* in_sizes, int n_in,
                              void* d_out, int out_size, void* d_ws, size_t ws_size,
                              hipStream_t stream) {
    const int*   x         = (const int*)d_in[0];
    const float* emb_table = (const float*)d_in[1];
    const float* lin_table = (const float*)d_in[2];
    const float* lin_bias  = (const float*)d_in[3];
    const float* W1        = (const float*)d_in[4];
    const float* b1        = (const float*)d_in[5];
    const float* w2        = (const float*)d_in[6];
    const float* proj_w    = (const float*)d_in[7];
    float* out = (float*)d_out;
    short* w1ws = (short*)d_ws;   // 4 KB prepacked W1 fragments

    prep_w1<<<1, 64, 0, stream>>>(W1, w1ws);
    afm_kernel<<<out_size, 256, 0, stream>>>(x, emb_table, lin_table, lin_bias,
                                             w1ws, b1, w2, proj_w, out);
}

// Round 3
// 521.036 us; speedup vs baseline: 1.0800x; 1.0703x over previous
//
#include <hip/hip_runtime.h>
#include <hip/hip_bf16.h>

#define NF 32      // fields
#define ED 64      // emb dim
#define AD 32      // attention dim
#define FD 50000   // field vocab
#define ROWP 68    // padded LDS emb row stride (floats): bank=(4*row+off)%32 -> <=2-way
#define SCP 36     // padded score row stride

typedef __attribute__((ext_vector_type(8))) short bf16x8;
typedef __attribute__((ext_vector_type(4))) float f32x4;

__device__ __forceinline__ short f2bf(float f) {
    union { float f; unsigned u; } v; v.f = f;
    unsigned r = v.u + 0x7fffu + ((v.u >> 16) & 1u);   // RNE
    return (short)(r >> 16);
}

// 8 floats -> 8 bf16 via packed HW converts (v_cvt_pk_bf16_f32)
__device__ __forceinline__ bf16x8 pack8(const float* p) {
    bf16x8 r;
#pragma unroll
    for (int i = 0; i < 4; ++i) {
        __hip_bfloat162 h = __float22bfloat162_rn(make_float2(p[2*i], p[2*i+1]));
        short2 s2 = *reinterpret_cast<short2*>(&h);
        r[2*i] = s2.x; r[2*i+1] = s2.y;
    }
    return r;
}

// One-wave setup: pre-pack W1 into bf16 MFMA fragment layout.
// Fragment (at,kk), lane l: f[jj] = W1[(kk*32+quad*8+jj)*AD + at*16 + l15]
//  == A-operand fragment of W1^T (rows a = at*16+l15, k = kk*32+quad*8+jj).
__global__ __launch_bounds__(64) void prep_w1(const float* __restrict__ W1,
                                              short* __restrict__ w1ws) {
    const int lane = threadIdx.x;
    const int l15 = lane & 15, quad = lane >> 4;
#pragma unroll
    for (int kk = 0; kk < 2; ++kk)
#pragma unroll
        for (int at = 0; at < 2; ++at) {
            bf16x8 f;
#pragma unroll
            for (int jj = 0; jj < 8; ++jj)
                f[jj] = f2bf(W1[(kk * 32 + quad * 8 + jj) * AD + at * 16 + l15]);
            *(bf16x8*)(w1ws + ((kk * 2 + at) * 64 + lane) * 8) = f;
        }
}

__global__ __launch_bounds__(256) void afm_kernel(
    const int* __restrict__ x,
    const float* __restrict__ emb_table,
    const float* __restrict__ lin_table,
    const float* __restrict__ lin_bias,
    const short* __restrict__ w1ws,
    const float* __restrict__ b1,
    const float* __restrict__ w2,
    const float* __restrict__ proj_w,
    float* __restrict__ out)
{
    __shared__ float s_emb[NF * ROWP];   // 8704 B
    __shared__ float s_sc[NF * SCP];     // unnormalized attn: exp(score), 0 where j<=i
    __shared__ float s_lin[NF];
    __shared__ float s_red[8];

    const int t    = threadIdx.x;
    const int lane = t & 63;
    const int wave = t >> 6;
    const int l15  = lane & 15;
    const int quad = lane >> 4;
    const int s    = blockIdx.x;

    // W1^T A-fragments: 4 coalesced 16B loads (L2-hit, prepacked)
    const bf16x8* wp = (const bf16x8*)w1ws;
    bf16x8 w1f[2][2];                    // [kk][at]
    w1f[0][0] = wp[0 * 64 + lane];
    w1f[0][1] = wp[1 * 64 + lane];
    w1f[1][0] = wp[2 * 64 + lane];
    w1f[1][1] = wp[3 * 64 + lane];
    // epilogue constants: lane handles attention rows a = at*16 + quad*4 + r
    float b1v[2][4], w2v[2][4];
#pragma unroll
    for (int at = 0; at < 2; ++at)
#pragma unroll
        for (int r = 0; r < 4; ++r) {
            const int a = at * 16 + quad * 4 + r;
            b1v[at][r] = b1[a];
            w2v[at][r] = w2[a];
        }

    // ---- stage 1: gather embeddings (coalesced: 8 threads per 256B row), lin, zero scores
    {
        const int row = t >> 3, part = t & 7;
        const int gidx = x[s * NF + row] + row * FD;
        const float* rp = emb_table + (size_t)gidx * ED + part * 8;
        float4 a = *(const float4*)rp;
        float4 b = *(const float4*)(rp + 4);
        *(float4*)(s_emb + row * ROWP + part * 8)     = a;
        *(float4*)(s_emb + row * ROWP + part * 8 + 4) = b;
        if (part == 0) s_lin[row] = lin_table[gidx];
    }
    for (int idx = t; idx < NF * SCP; idx += 256) s_sc[idx] = 0.f;
    __syncthreads();

    // ---- E fragments (fp32): lane holds e_{16*jb+l15}[kk*32+quad*8+jj]
    float ef[2][2][8];
#pragma unroll
    for (int jb = 0; jb < 2; ++jb)
#pragma unroll
        for (int kk = 0; kk < 2; ++kk) {
            const float* p = s_emb + (16 * jb + l15) * ROWP + kk * 32 + quad * 8;
            *(float4*)&ef[jb][kk][0] = *(const float4*)p;
            *(float4*)&ef[jb][kk][4] = *(const float4*)(p + 4);
        }

    // ---- pair GEMMs: H^T = W1^T (A) x P^T (B); C[a][p]: p=l15, a=at*16+quad*4+r
    float lsum = 0.f;
    for (int i = wave; i < NF; i += 4) {
        float ei[2][8];
#pragma unroll
        for (int kk = 0; kk < 2; ++kk) {
            const float* p = s_emb + i * ROWP + kk * 32 + quad * 8;  // quad-broadcast
            *(float4*)&ei[kk][0] = *(const float4*)p;
            *(float4*)&ei[kk][4] = *(const float4*)(p + 4);
        }
#pragma unroll
        for (int jb = 0; jb < 2; ++jb) {
            if (jb * 16 + 15 <= i) continue;    // tile has no j>i rows
            f32x4 acc0 = {0.f,0.f,0.f,0.f}, acc1 = {0.f,0.f,0.f,0.f};
#pragma unroll
            for (int kk = 0; kk < 2; ++kk) {
                float pr[8];
#pragma unroll
                for (int z = 0; z < 8; ++z) pr[z] = ei[kk][z] * ef[jb][kk][z];
                bf16x8 bfrag = pack8(pr);
                acc0 = __builtin_amdgcn_mfma_f32_16x16x32_bf16(w1f[kk][0], bfrag, acc0, 0, 0, 0);
                acc1 = __builtin_amdgcn_mfma_f32_16x16x32_bf16(w1f[kk][1], bfrag, acc1, 0, 0, 0);
            }
            // score[p=l15] = sum_a relu(H^T[a][p]+b1[a])*w2[a]: 8 in-register + 2 shfl
            float v = 0.f;
#pragma unroll
            for (int r = 0; r < 4; ++r) {
                v += fmaxf(acc0[r] + b1v[0][r], 0.f) * w2v[0][r];
                v += fmaxf(acc1[r] + b1v[1][r], 0.f) * w2v[1][r];
            }
            v += __shfl_xor(v, 16);
            v += __shfl_xor(v, 32);     // all quads now hold the full score
            const int j = jb * 16 + l15;
            float e = (j > i) ? __expf(v) : 0.f;   // scores ~1e-4: no max needed
            lsum += e;                  // identical across quads
            if (quad == 0) s_sc[i * SCP + jb * 16 + l15] = e;
        }
    }
    // lsum identical across quads -> reduce over 16 lanes only
    lsum += __shfl_xor(lsum, 1);
    lsum += __shfl_xor(lsum, 2);
    lsum += __shfl_xor(lsum, 4);
    lsum += __shfl_xor(lsum, 8);
    if (lane == 0) s_red[4 + wave] = lsum;   // exact partial sum
    __syncthreads();

    // ---- U = Attn(unnorm) @ E via MFMA; wave w owns d-cols 16w..16w+15
    const int dcol = wave * 16 + l15;
    float bEv[8];
#pragma unroll
    for (int jj = 0; jj < 8; ++jj)
        bEv[jj] = s_emb[(quad * 8 + jj) * ROWP + dcol];
    bf16x8 bE = pack8(bEv);
    float sec = 0.f;
#pragma unroll
    for (int mt = 0; mt < 2; ++mt) {
        const float* ap = s_sc + (16 * mt + l15) * SCP + quad * 8;
        float av[8];
        *(float4*)&av[0] = *(const float4*)ap;
        *(float4*)&av[4] = *(const float4*)(ap + 4);
        bf16x8 aA = pack8(av);
        f32x4 u = {0.f,0.f,0.f,0.f};
        u = __builtin_amdgcn_mfma_f32_16x16x32_bf16(aA, bE, u, 0, 0, 0);
#pragma unroll
        for (int r = 0; r < 4; ++r)
            sec += u[r] * s_emb[(16 * mt + quad * 4 + r) * ROWP + dcol]; // e_i[d]*u_i[d]
    }
    sec *= proj_w[dcol];
#pragma unroll
    for (int d = 1; d < 64; d <<= 1) sec += __shfl_xor(sec, d);
    if (lane == 0) s_red[wave] = sec;
    __syncthreads();

    if (t == 0) {
        float S = s_red[4] + s_red[5] + s_red[6] + s_red[7];
        float second = (s_red[0] + s_red[1] + s_red[2] + s_red[3]) / S;
        float first = lin_bias[0];
#pragma unroll
        for (int f = 0; f < NF; ++f) first += s_lin[f];
        float y = first + second;
        out[s] = 1.f / (1.f + __expf(-y));
    }
}

extern "C" void kernel_launch(void* const* d_in, const int* in_sizes, int n_in,
                              void* d_out, int out_size, void* d_ws, size_t ws_size,
                              hipStream_t stream) {
    const int*   x         = (const int*)d_in[0];
    const float* emb_table = (const float*)d_in[1];
    const float* lin_table = (const float*)d_in[2];
    const float* lin_bias  = (const float*)d_in[3];
    const float* W1        = (const float*)d_in[4];
    const float* b1        = (const float*)d_in[5];
    const float* w2        = (const float*)d_in[6];
    const float* proj_w    = (const float*)d_in[7];
    float* out = (float*)d_out;
    short* w1ws = (short*)d_ws;   // 4 KB prepacked W1 fragments

    prep_w1<<<1, 64, 0, stream>>>(W1, w1ws);
    afm_kernel<<<out_size, 256, 0, stream>>>(x, emb_table, lin_table, lin_bias,
                                             w1ws, b1, w2, proj_w, out);
}